// Round 4
// baseline (244.205 us; speedup 1.0000x reference)
//
#include <hip/hip_runtime.h>
#include <hip/hip_bf16.h>
#include <cstdint>
#include <cstddef>

#define BB 2
#define SS 2048
#define DD 1024
#define HH 16
#define EE 64

typedef short bf16x8 __attribute__((ext_vector_type(8)));
typedef short s4 __attribute__((ext_vector_type(4)));
typedef float f32x4 __attribute__((ext_vector_type(4)));
typedef float float4v __attribute__((ext_vector_type(4)));

#define GLDS(gp, lp) __builtin_amdgcn_global_load_lds( \
    (const __attribute__((address_space(1))) void*)(gp), \
    (__attribute__((address_space(3))) void*)(lp), 16, 0, 0)

static __device__ __forceinline__ short f2bf(float f) {
    union { float f; uint32_t u; } v; v.f = f;
    uint32_t r = (v.u + 0x7fffu + ((v.u >> 16) & 1u)) >> 16;
    return (short)r;
}

// ---------------- fp32 -> bf16 convert (vectorized) ----------------
__global__ void convert_x_kernel(const float* __restrict__ x, short* __restrict__ xb, int n4) {
    int i = blockIdx.x * blockDim.x + threadIdx.x;
    if (i >= n4) return;
    float4v v = ((const float4v*)x)[i];
    s4 o; o[0] = f2bf(v[0]); o[1] = f2bf(v[1]); o[2] = f2bf(v[2]); o[3] = f2bf(v[3]);
    ((s4*)xb)[i] = o;
}

// ------------- weight transpose+convert: [R x 64] -> [64 x R] bf16 -------------
__global__ void transpose_w_kernel(const float* __restrict__ src, short* __restrict__ dst, int R) {
    __shared__ float tile[64][65];
    int mtx = blockIdx.y;
    int r0 = blockIdx.x * 64;
    const float* s = src + (size_t)mtx * R * 64;
    short* d = dst + (size_t)mtx * R * 64;
    int t = threadIdx.x;
#pragma unroll
    for (int i = 0; i < 16; ++i) {
        int idx = t + i * 256;
        int r = idx >> 6, c = idx & 63;
        tile[r][c] = s[(size_t)(r0 + r) * 64 + c];
    }
    __syncthreads();
#pragma unroll
    for (int i = 0; i < 16; ++i) {
        int idx = t + i * 256;
        int e = idx >> 6, dd2 = idx & 63;
        d[(size_t)e * R + r0 + dd2] = f2bf(tile[dd2][e]);
    }
}

// ------------- QKV as one m97-style GEMM -------------
__global__ __launch_bounds__(256) void qkv_gemm(const short* __restrict__ A,
                                                const short* __restrict__ Bt,
                                                short* __restrict__ Qo,
                                                short* __restrict__ Ko,
                                                short* __restrict__ Vto) {
    __shared__ short As[128 * 32];
    __shared__ short Bs[128 * 32];
    int tid = threadIdx.x;
    int wv = tid >> 6, lane = tid & 63;
    int m = lane & 15, g = lane >> 4;
    int wr = wv >> 1, wc = wv & 1;

    int wg = (blockIdx.x & 7) * 96 + (blockIdx.x >> 3);
    int mb = wg / 24, nb = wg % 24;
    int rowBase = mb * 128, colBase0 = nb * 128;

    int strow = wv * 16 + (lane >> 2);
    int stcol = (lane & 3) * 8;
    const short* a0 = A + (size_t)(rowBase + strow) * DD + stcol;
    const short* b0 = Bt + (size_t)(colBase0 + strow) * DD + stcol;
    short* AsW0 = As + wv * 512;
    short* AsW1 = As + (4 + wv) * 512;
    short* BsW0 = Bs + wv * 512;
    short* BsW1 = Bs + (4 + wv) * 512;

    f32x4 acc[4][4];
#pragma unroll
    for (int i = 0; i < 4; ++i)
#pragma unroll
        for (int j = 0; j < 4; ++j) acc[i][j] = {0, 0, 0, 0};

    for (int kt = 0; kt < DD; kt += 32) {
        __syncthreads();
        GLDS(a0 + kt, AsW0);
        GLDS(a0 + kt + (size_t)64 * DD, AsW1);
        GLDS(b0 + kt, BsW0);
        GLDS(b0 + kt + (size_t)64 * DD, BsW1);
        __syncthreads();

        bf16x8 af[4], bfr[4];
#pragma unroll
        for (int mi = 0; mi < 4; ++mi)
            af[mi] = *(const bf16x8*)&As[(wr * 64 + mi * 16 + m) * 32 + g * 8];
#pragma unroll
        for (int ni = 0; ni < 4; ++ni)
            bfr[ni] = *(const bf16x8*)&Bs[(wc * 64 + ni * 16 + m) * 32 + g * 8];
#pragma unroll
        for (int mi = 0; mi < 4; ++mi)
#pragma unroll
            for (int ni = 0; ni < 4; ++ni)
                acc[mi][ni] = __builtin_amdgcn_mfma_f32_16x16x32_bf16(af[mi], bfr[ni], acc[mi][ni], 0, 0, 0);
    }

    int colBase = colBase0 + wc * 64;
    int mtx = colBase >> 10;
    int h = (colBase >> 6) & 15;
    int rb = rowBase + wr * 64;

    if (mtx == 0) {
#pragma unroll
        for (int mi = 0; mi < 4; ++mi)
#pragma unroll
            for (int ni = 0; ni < 4; ++ni)
#pragma unroll
                for (int r = 0; r < 4; ++r) {
                    int row = rb + mi * 16 + g * 4 + r;
                    int b = row >> 11, s = row & 2047;
                    Qo[((size_t)(b * HH + h) * SS + s) * EE + ni * 16 + m] = f2bf(acc[mi][ni][r] * 0.125f);
                }
    } else if (mtx == 1) {
#pragma unroll
        for (int mi = 0; mi < 4; ++mi)
#pragma unroll
            for (int ni = 0; ni < 4; ++ni)
#pragma unroll
                for (int r = 0; r < 4; ++r) {
                    int row = rb + mi * 16 + g * 4 + r;
                    int b = row >> 11, s = row & 2047;
                    Ko[((size_t)(b * HH + h) * SS + s) * EE + ni * 16 + m] = f2bf(acc[mi][ni][r]);
                }
    } else {
#pragma unroll
        for (int mi = 0; mi < 4; ++mi)
#pragma unroll
            for (int ni = 0; ni < 4; ++ni) {
                int row0 = rb + mi * 16 + g * 4;
                int b = row0 >> 11, s = row0 & 2047;
                s4 o; o[0] = f2bf(acc[mi][ni][0]); o[1] = f2bf(acc[mi][ni][1]);
                o[2] = f2bf(acc[mi][ni][2]); o[3] = f2bf(acc[mi][ni][3]);
                *(s4*)&Vto[((size_t)(b * HH + h) * EE + ni * 16 + m) * SS + s] = o;
            }
    }
}

// ------------- flash attention (causal), swapped-QK^T lane-local softmax -------------
// One wave per 16 q-rows; lane (m,g) owns row q=q0+m's scores for t = n*16+g*4+r.
// S^T = mfma(K,Q); softmax in-register (2 shuffles/tile for max, 0 for sum);
// P via 4x ds_write_b64 + 2x ds_read_b128; PV as mfma(V^T, P) -> o^T; defer-max THR=8.
__global__ __launch_bounds__(256) void attn_kernel(const short* __restrict__ Q,
                                                   const short* __restrict__ K,
                                                   const short* __restrict__ Vt,
                                                   short* __restrict__ ctx) {
    __shared__ short pl[4][16][72];     // per-wave P tile [q][t], 144B rows (16B aligned)
    int wv = threadIdx.x >> 6, lane = threadIdx.x & 63;
    int m = lane & 15, g = lane >> 4;
    int W = blockIdx.x * 4 + wv;
    int qg = 127 - (W >> 5);            // heavy-first
    int bh = W & 31;
    int b = bh >> 4, h = bh & 15;
    const short* Qb = Q + (size_t)bh * SS * EE;
    const short* Kb = K + (size_t)bh * SS * EE;
    const short* Vb = Vt + (size_t)bh * EE * SS;
    int q0 = qg * 16;

    bf16x8 qa0 = *(const bf16x8*)(Qb + (size_t)(q0 + m) * EE + g * 8);
    bf16x8 qa1 = *(const bf16x8*)(Qb + (size_t)(q0 + m) * EE + 32 + g * 8);

    float mreg = -INFINITY, lsum = 0.f;
    f32x4 o[4];
#pragma unroll
    for (int n = 0; n < 4; ++n) { o[n][0] = 0.f; o[n][1] = 0.f; o[n][2] = 0.f; o[n][3] = 0.f; }

    int dtile = qg >> 2;
    for (int tt = 0; tt <= dtile; ++tt) {
        int t0 = tt * 64;

        // S^T = K (A-frag) x Q (B-frag): lane (m,g) reg r of s[n] = score(q=q0+m, t=t0+n*16+g*4+r)
        f32x4 s[4] = {{0,0,0,0},{0,0,0,0},{0,0,0,0},{0,0,0,0}};
#pragma unroll
        for (int n = 0; n < 4; ++n) {
            bf16x8 kb0 = *(const bf16x8*)(Kb + (size_t)(t0 + n * 16 + m) * EE + g * 8);
            s[n] = __builtin_amdgcn_mfma_f32_16x16x32_bf16(kb0, qa0, s[n], 0, 0, 0);
            bf16x8 kb1 = *(const bf16x8*)(Kb + (size_t)(t0 + n * 16 + m) * EE + 32 + g * 8);
            s[n] = __builtin_amdgcn_mfma_f32_16x16x32_bf16(kb1, qa1, s[n], 0, 0, 0);
        }

        if (tt == dtile) {
#pragma unroll
            for (int n = 0; n < 4; ++n)
#pragma unroll
                for (int r = 0; r < 4; ++r)
                    if (t0 + n * 16 + g * 4 + r > q0 + m) s[n][r] = -INFINITY;
        }

        // row max: 15 in-lane fmax + 2 shuffles (reduce over g)
        float mx = s[0][0];
#pragma unroll
        for (int n = 0; n < 4; ++n)
#pragma unroll
            for (int r = 0; r < 4; ++r) mx = fmaxf(mx, s[n][r]);
        mx = fmaxf(mx, __shfl_xor(mx, 16, 64));
        mx = fmaxf(mx, __shfl_xor(mx, 32, 64));

        // defer-max: rescale only if max grew by > 8 anywhere in the wave
        if (!__all(mx <= mreg + 8.0f)) {
            float mn = fmaxf(mreg, mx);
            float al = __expf(mreg - mn);
            lsum *= al;
#pragma unroll
            for (int n = 0; n < 4; ++n)
#pragma unroll
                for (int r = 0; r < 4; ++r) o[n][r] *= al;
            mreg = mn;
        }

        // exp, per-lane partial sum, pack P to LDS (row q=m, packed quads)
#pragma unroll
        for (int n = 0; n < 4; ++n) {
            s4 pk;
#pragma unroll
            for (int r = 0; r < 4; ++r) {
                float p = __expf(s[n][r] - mreg);
                lsum += p;
                pk[r] = f2bf(p);
            }
            *(s4*)&pl[wv][m][n * 16 + g * 4] = pk;
        }

        // PV: o^T[e][q] += V^T (A-frag) x P (B-frag)
#pragma unroll
        for (int ks = 0; ks < 2; ++ks) {
            bf16x8 pa = *(const bf16x8*)&pl[wv][m][ks * 32 + g * 8];
#pragma unroll
            for (int n = 0; n < 4; ++n) {
                bf16x8 vb = *(const bf16x8*)(Vb + (size_t)(n * 16 + m) * SS + t0 + ks * 32 + g * 8);
                o[n] = __builtin_amdgcn_mfma_f32_16x16x32_bf16(vb, pa, o[n], 0, 0, 0);
            }
        }
    }

    // final row-sum reduce + normalized vectorized write
    lsum += __shfl_xor(lsum, 16, 64);
    lsum += __shfl_xor(lsum, 32, 64);
    float inv = 1.0f / lsum;
    short* cb = ctx + (size_t)(b * SS + q0 + m) * (HH * EE) + h * EE;
#pragma unroll
    for (int n = 0; n < 4; ++n) {
        s4 pk;
#pragma unroll
        for (int r = 0; r < 4; ++r) pk[r] = f2bf(o[n][r] * inv);
        *(s4*)&cb[n * 16 + g * 4] = pk;
    }
}

// ------------- output projection: ctx [4096,1024] @ W [1024,64] -> out fp32 -------------
__global__ __launch_bounds__(256) void outproj_kernel(const short* __restrict__ ctx,
                                                      const short* __restrict__ wot,
                                                      float* __restrict__ out) {
    int wv = threadIdx.x >> 6, lane = threadIdx.x & 63;
    int m = lane & 15, g = lane >> 4;
    int r0 = blockIdx.x * 64 + wv * 16;
    const short* arow = ctx + (size_t)(r0 + m) * (HH * EE) + g * 8;
    const short* wb = wot + g * 8;
    f32x4 acc[4] = {{0,0,0,0},{0,0,0,0},{0,0,0,0},{0,0,0,0}};
    for (int d0 = 0; d0 < HH * EE; d0 += 32) {
        bf16x8 a = *(const bf16x8*)(arow + d0);
#pragma unroll
        for (int n = 0; n < 4; ++n) {
            bf16x8 bbf = *(const bf16x8*)(wb + (size_t)(n * 16 + m) * (HH * EE) + d0);
            acc[n] = __builtin_amdgcn_mfma_f32_16x16x32_bf16(a, bbf, acc[n], 0, 0, 0);
        }
    }
    float* orow = out + (size_t)r0 * EE;
#pragma unroll
    for (int n = 0; n < 4; ++n)
#pragma unroll
        for (int r = 0; r < 4; ++r)
            orow[(size_t)(g * 4 + r) * EE + n * 16 + m] = acc[n][r];
}

extern "C" void kernel_launch(void* const* d_in, const int* in_sizes, int n_in,
                              void* d_out, int out_size, void* d_ws, size_t ws_size,
                              hipStream_t stream) {
    const float* x  = (const float*)d_in[0];
    const float* Wq = (const float*)d_in[1];
    const float* Wk = (const float*)d_in[2];
    const float* Wv = (const float*)d_in[3];
    const float* W  = (const float*)d_in[4];
    float* out = (float*)d_out;

    char* w = (char*)d_ws;
    short* xb  = (short*)w;                                   // 8 MB
    short* wqt = (short*)(w + ((size_t)8 << 20));             // 2 MB each, contiguous = Bt
    short* wkt = wqt + (size_t)HH * EE * DD;
    short* wvt = wkt + (size_t)HH * EE * DD;
    short* wot = wvt + (size_t)HH * EE * DD;                  // 128 KB
    short* Qb  = wot + (size_t)64 * 1024;                     // 8 MB each
    short* Kb  = Qb + (size_t)BB * HH * SS * EE;
    short* Vtb = Kb + (size_t)BB * HH * SS * EE;
    short* ctx = Vtb + (size_t)BB * HH * SS * EE;             // 8 MB

    int n4 = BB * SS * DD / 4;
    convert_x_kernel<<<n4 / 256, 256, 0, stream>>>(x, xb, n4);
    transpose_w_kernel<<<dim3(16, 16), 256, 0, stream>>>(Wq, wqt, DD);
    transpose_w_kernel<<<dim3(16, 16), 256, 0, stream>>>(Wk, wkt, DD);
    transpose_w_kernel<<<dim3(16, 16), 256, 0, stream>>>(Wv, wvt, DD);
    transpose_w_kernel<<<dim3(16, 1), 256, 0, stream>>>(W, wot, HH * EE);

    qkv_gemm<<<768, 256, 0, stream>>>(xb, wqt, Qb, Kb, Vtb);
    attn_kernel<<<1024, 256, 0, stream>>>(Qb, Kb, Vtb, ctx);
    outproj_kernel<<<64, 256, 0, stream>>>(ctx, wot, out);
}

// Round 5
// 143.929 us; speedup vs baseline: 1.6967x; 1.6967x over previous
//
#include <hip/hip_runtime.h>
#include <hip/hip_bf16.h>
#include <cstdint>
#include <cstddef>

#define BB 2
#define SS 2048
#define DD 1024
#define HH 16
#define EE 64

typedef short bf16x8 __attribute__((ext_vector_type(8)));
typedef short s4 __attribute__((ext_vector_type(4)));
typedef float f32x4 __attribute__((ext_vector_type(4)));
typedef float float4v __attribute__((ext_vector_type(4)));

#define GLDS(gp, lp) __builtin_amdgcn_global_load_lds( \
    (const __attribute__((address_space(1))) void*)(gp), \
    (__attribute__((address_space(3))) void*)(lp), 16, 0, 0)

static __device__ __forceinline__ short f2bf(float f) {
    union { float f; uint32_t u; } v; v.f = f;
    uint32_t r = (v.u + 0x7fffu + ((v.u >> 16) & 1u)) >> 16;
    return (short)r;
}

// ---------------- fp32 -> bf16 convert (vectorized) ----------------
__global__ void convert_x_kernel(const float* __restrict__ x, short* __restrict__ xb, int n4) {
    int i = blockIdx.x * blockDim.x + threadIdx.x;
    if (i >= n4) return;
    float4v v = ((const float4v*)x)[i];
    s4 o; o[0] = f2bf(v[0]); o[1] = f2bf(v[1]); o[2] = f2bf(v[2]); o[3] = f2bf(v[3]);
    ((s4*)xb)[i] = o;
}

// ------------- weight transpose+convert: [R x 64] -> [64 x R] bf16 -------------
__global__ void transpose_w_kernel(const float* __restrict__ src, short* __restrict__ dst, int R) {
    __shared__ float tile[64][65];
    int mtx = blockIdx.y;
    int r0 = blockIdx.x * 64;
    const float* s = src + (size_t)mtx * R * 64;
    short* d = dst + (size_t)mtx * R * 64;
    int t = threadIdx.x;
#pragma unroll
    for (int i = 0; i < 16; ++i) {
        int idx = t + i * 256;
        int r = idx >> 6, c = idx & 63;
        tile[r][c] = s[(size_t)(r0 + r) * 64 + c];
    }
    __syncthreads();
#pragma unroll
    for (int i = 0; i < 16; ++i) {
        int idx = t + i * 256;
        int e = idx >> 6, dd2 = idx & 63;
        d[(size_t)e * R + r0 + dd2] = f2bf(tile[dd2][e]);
    }
}

// ------------- QKV as one m97-style GEMM -------------
__global__ __launch_bounds__(256) void qkv_gemm(const short* __restrict__ A,
                                                const short* __restrict__ Bt,
                                                short* __restrict__ Qo,
                                                short* __restrict__ Ko,
                                                short* __restrict__ Vto) {
    __shared__ short As[128 * 32];
    __shared__ short Bs[128 * 32];
    int tid = threadIdx.x;
    int wv = tid >> 6, lane = tid & 63;
    int m = lane & 15, g = lane >> 4;
    int wr = wv >> 1, wc = wv & 1;

    int wg = (blockIdx.x & 7) * 96 + (blockIdx.x >> 3);
    int mb = wg / 24, nb = wg % 24;
    int rowBase = mb * 128, colBase0 = nb * 128;

    int strow = wv * 16 + (lane >> 2);
    int stcol = (lane & 3) * 8;
    const short* a0 = A + (size_t)(rowBase + strow) * DD + stcol;
    const short* b0 = Bt + (size_t)(colBase0 + strow) * DD + stcol;
    short* AsW0 = As + wv * 512;
    short* AsW1 = As + (4 + wv) * 512;
    short* BsW0 = Bs + wv * 512;
    short* BsW1 = Bs + (4 + wv) * 512;

    f32x4 acc[4][4];
#pragma unroll
    for (int i = 0; i < 4; ++i)
#pragma unroll
        for (int j = 0; j < 4; ++j) acc[i][j] = {0, 0, 0, 0};

    for (int kt = 0; kt < DD; kt += 32) {
        __syncthreads();
        GLDS(a0 + kt, AsW0);
        GLDS(a0 + kt + (size_t)64 * DD, AsW1);
        GLDS(b0 + kt, BsW0);
        GLDS(b0 + kt + (size_t)64 * DD, BsW1);
        __syncthreads();

        bf16x8 af[4], bfr[4];
#pragma unroll
        for (int mi = 0; mi < 4; ++mi)
            af[mi] = *(const bf16x8*)&As[(wr * 64 + mi * 16 + m) * 32 + g * 8];
#pragma unroll
        for (int ni = 0; ni < 4; ++ni)
            bfr[ni] = *(const bf16x8*)&Bs[(wc * 64 + ni * 16 + m) * 32 + g * 8];
#pragma unroll
        for (int mi = 0; mi < 4; ++mi)
#pragma unroll
            for (int ni = 0; ni < 4; ++ni)
                acc[mi][ni] = __builtin_amdgcn_mfma_f32_16x16x32_bf16(af[mi], bfr[ni], acc[mi][ni], 0, 0, 0);
    }

    int colBase = colBase0 + wc * 64;
    int mtx = colBase >> 10;
    int h = (colBase >> 6) & 15;
    int rb = rowBase + wr * 64;

    if (mtx == 0) {
#pragma unroll
        for (int mi = 0; mi < 4; ++mi)
#pragma unroll
            for (int ni = 0; ni < 4; ++ni)
#pragma unroll
                for (int r = 0; r < 4; ++r) {
                    int row = rb + mi * 16 + g * 4 + r;
                    int b = row >> 11, s = row & 2047;
                    Qo[((size_t)(b * HH + h) * SS + s) * EE + ni * 16 + m] = f2bf(acc[mi][ni][r] * 0.125f);
                }
    } else if (mtx == 1) {
#pragma unroll
        for (int mi = 0; mi < 4; ++mi)
#pragma unroll
            for (int ni = 0; ni < 4; ++ni)
#pragma unroll
                for (int r = 0; r < 4; ++r) {
                    int row = rb + mi * 16 + g * 4 + r;
                    int b = row >> 11, s = row & 2047;
                    Ko[((size_t)(b * HH + h) * SS + s) * EE + ni * 16 + m] = f2bf(acc[mi][ni][r]);
                }
    } else {
#pragma unroll
        for (int mi = 0; mi < 4; ++mi)
#pragma unroll
            for (int ni = 0; ni < 4; ++ni) {
                int row0 = rb + mi * 16 + g * 4;
                int b = row0 >> 11, s = row0 & 2047;
                s4 o; o[0] = f2bf(acc[mi][ni][0]); o[1] = f2bf(acc[mi][ni][1]);
                o[2] = f2bf(acc[mi][ni][2]); o[3] = f2bf(acc[mi][ni][3]);
                *(s4*)&Vto[((size_t)(b * HH + h) * EE + ni * 16 + m) * SS + s] = o;
            }
    }
}

// ------------- flash attention (causal), block-cooperative staged K/V -------------
// Block = 4 waves = 64 q-rows of one head (wave wv: rows qblk*64+wv*16..+15).
// All waves share ntile = qblk+1 (perfect balance). K/V tiles staged into
// double-buffered LDS via global_load_lds (2-phase prefetch), XOR-swizzled
// (byte ^= ((row&7)<<4)) with inverse-swizzled global source (both-sides rule).
// Swapped QK^T lane-local softmax, defer-max THR=8, PV as mfma(V^T, P).
__global__ __launch_bounds__(256) void attn_kernel(const short* __restrict__ Q,
                                                   const short* __restrict__ K,
                                                   const short* __restrict__ Vt,
                                                   short* __restrict__ ctx) {
    __shared__ short Ks[2][64 * 64];    // [t][e], 128B rows, swizzled
    __shared__ short Vs[2][64 * 64];    // [e][t], 128B rows, swizzled
    __shared__ short pl[4][16][72];     // per-wave P tile
    int tid = threadIdx.x;
    int wv = tid >> 6, lane = tid & 63;
    int m = lane & 15, g = lane >> 4;
    int bid = blockIdx.x;
    int qblk = 31 - (bid >> 5);         // heavy-first
    int bh = bid & 31;
    int b = bh >> 4, h = bh & 15;
    const short* Qb = Q + (size_t)bh * SS * EE;
    const short* Kb = K + (size_t)bh * SS * EE;
    const short* Vb = Vt + (size_t)bh * EE * SS;
    int qrow = qblk * 64 + wv * 16 + m;

    // staging geometry: thread covers LDS rows srow / srow+32, 16B slot (lane&7)
    int srow = wv * 8 + (lane >> 3);
    int scol_s = (((lane & 7) * 16) ^ ((srow & 7) << 4)) >> 1;   // inverse-swizzled source col (shorts)

    bf16x8 qa0 = *(const bf16x8*)(Qb + (size_t)qrow * EE + g * 8);
    bf16x8 qa1 = *(const bf16x8*)(Qb + (size_t)qrow * EE + 32 + g * 8);

    // swizzled read offsets (bytes within a 128B row)
    int sw = (m & 7) << 4;
    int c0 = (g * 16) ^ sw;
    int c1 = (64 + g * 16) ^ sw;

    float mreg = -INFINITY, lsum = 0.f;
    f32x4 o[4];
#pragma unroll
    for (int n = 0; n < 4; ++n) { o[n][0] = 0.f; o[n][1] = 0.f; o[n][2] = 0.f; o[n][3] = 0.f; }

    auto STAGE = [&](int nb, int t0) {
        short* kd = &Ks[0][0] + nb * 4096 + wv * 512;
        short* vd = &Vs[0][0] + nb * 4096 + wv * 512;
        const short* ksrc = Kb + (size_t)(t0 + srow) * EE + scol_s;
        const short* vsrc = Vb + (size_t)srow * SS + t0 + scol_s;
        GLDS(ksrc, kd);
        GLDS(ksrc + 32 * EE, kd + 2048);
        GLDS(vsrc, vd);
        GLDS(vsrc + (size_t)32 * SS, vd + 2048);
    };

    int ntile = qblk + 1;
    STAGE(0, 0);
    __syncthreads();

    for (int tt = 0; tt < ntile; ++tt) {
        if (tt + 1 < ntile) STAGE((tt + 1) & 1, (tt + 1) * 64);
        int t0 = tt * 64;
        const short* Ksb = &Ks[0][0] + (tt & 1) * 4096;
        const short* Vsb = &Vs[0][0] + (tt & 1) * 4096;

        // S^T = K x Q: lane (m,g) holds score(q=qrow, t=t0+n*16+g*4+r)
        f32x4 s[4] = {{0,0,0,0},{0,0,0,0},{0,0,0,0},{0,0,0,0}};
#pragma unroll
        for (int n = 0; n < 4; ++n) {
            const char* krow = (const char*)(Ksb + (n * 16 + m) * 64);
            bf16x8 kb0 = *(const bf16x8*)(krow + c0);
            s[n] = __builtin_amdgcn_mfma_f32_16x16x32_bf16(kb0, qa0, s[n], 0, 0, 0);
            bf16x8 kb1 = *(const bf16x8*)(krow + c1);
            s[n] = __builtin_amdgcn_mfma_f32_16x16x32_bf16(kb1, qa1, s[n], 0, 0, 0);
        }

        if (tt == qblk) {
#pragma unroll
            for (int n = 0; n < 4; ++n)
#pragma unroll
                for (int r = 0; r < 4; ++r)
                    if (t0 + n * 16 + g * 4 + r > qrow) s[n][r] = -INFINITY;
        }

        // row max: 15 in-lane fmax + 2 shuffles
        float mx = s[0][0];
#pragma unroll
        for (int n = 0; n < 4; ++n)
#pragma unroll
            for (int r = 0; r < 4; ++r) mx = fmaxf(mx, s[n][r]);
        mx = fmaxf(mx, __shfl_xor(mx, 16, 64));
        mx = fmaxf(mx, __shfl_xor(mx, 32, 64));

        // defer-max
        if (!__all(mx <= mreg + 8.0f)) {
            float mn = fmaxf(mreg, mx);
            float al = __expf(mreg - mn);
            lsum *= al;
#pragma unroll
            for (int n = 0; n < 4; ++n)
#pragma unroll
                for (int r = 0; r < 4; ++r) o[n][r] *= al;
            mreg = mn;
        }

        // exp + partial sum + P pack to LDS
#pragma unroll
        for (int n = 0; n < 4; ++n) {
            s4 pk;
#pragma unroll
            for (int r = 0; r < 4; ++r) {
                float p = __expf(s[n][r] - mreg);
                lsum += p;
                pk[r] = f2bf(p);
            }
            *(s4*)&pl[wv][m][n * 16 + g * 4] = pk;
        }

        // PV: o^T += V^T x P
#pragma unroll
        for (int ks = 0; ks < 2; ++ks) {
            bf16x8 pa = *(const bf16x8*)&pl[wv][m][ks * 32 + g * 8];
            int cv = ks ? c1 : c0;
#pragma unroll
            for (int n = 0; n < 4; ++n) {
                const char* vrow = (const char*)(Vsb + (n * 16 + m) * 64);
                bf16x8 vb = *(const bf16x8*)(vrow + cv);
                o[n] = __builtin_amdgcn_mfma_f32_16x16x32_bf16(vb, pa, o[n], 0, 0, 0);
            }
        }

        __syncthreads();   // drains STAGE vmcnt + protects buffer reuse
    }

    // final reduce + write
    lsum += __shfl_xor(lsum, 16, 64);
    lsum += __shfl_xor(lsum, 32, 64);
    float inv = 1.0f / lsum;
    short* cb = ctx + (size_t)(b * SS + qrow) * (HH * EE) + h * EE;
#pragma unroll
    for (int n = 0; n < 4; ++n) {
        s4 pk;
#pragma unroll
        for (int r = 0; r < 4; ++r) pk[r] = f2bf(o[n][r] * inv);
        *(s4*)&cb[n * 16 + g * 4] = pk;
    }
}

// ------------- output projection: ctx [4096,1024] @ W [1024,64] -> out fp32 -------------
__global__ __launch_bounds__(256) void outproj_kernel(const short* __restrict__ ctx,
                                                      const short* __restrict__ wot,
                                                      float* __restrict__ out) {
    int wv = threadIdx.x >> 6, lane = threadIdx.x & 63;
    int m = lane & 15, g = lane >> 4;
    int r0 = blockIdx.x * 64 + wv * 16;
    const short* arow = ctx + (size_t)(r0 + m) * (HH * EE) + g * 8;
    const short* wb = wot + g * 8;
    f32x4 acc[4] = {{0,0,0,0},{0,0,0,0},{0,0,0,0},{0,0,0,0}};
    for (int d0 = 0; d0 < HH * EE; d0 += 32) {
        bf16x8 a = *(const bf16x8*)(arow + d0);
#pragma unroll
        for (int n = 0; n < 4; ++n) {
            bf16x8 bbf = *(const bf16x8*)(wb + (size_t)(n * 16 + m) * (HH * EE) + d0);
            acc[n] = __builtin_amdgcn_mfma_f32_16x16x32_bf16(a, bbf, acc[n], 0, 0, 0);
        }
    }
    float* orow = out + (size_t)r0 * EE;
#pragma unroll
    for (int n = 0; n < 4; ++n)
#pragma unroll
        for (int r = 0; r < 4; ++r)
            orow[(size_t)(g * 4 + r) * EE + n * 16 + m] = acc[n][r];
}

extern "C" void kernel_launch(void* const* d_in, const int* in_sizes, int n_in,
                              void* d_out, int out_size, void* d_ws, size_t ws_size,
                              hipStream_t stream) {
    const float* x  = (const float*)d_in[0];
    const float* Wq = (const float*)d_in[1];
    const float* Wk = (const float*)d_in[2];
    const float* Wv = (const float*)d_in[3];
    const float* W  = (const float*)d_in[4];
    float* out = (float*)d_out;

    char* w = (char*)d_ws;
    short* xb  = (short*)w;                                   // 8 MB
    short* wqt = (short*)(w + ((size_t)8 << 20));             // 2 MB each, contiguous = Bt
    short* wkt = wqt + (size_t)HH * EE * DD;
    short* wvt = wkt + (size_t)HH * EE * DD;
    short* wot = wvt + (size_t)HH * EE * DD;                  // 128 KB
    short* Qb  = wot + (size_t)64 * 1024;                     // 8 MB each
    short* Kb  = Qb + (size_t)BB * HH * SS * EE;
    short* Vtb = Kb + (size_t)BB * HH * SS * EE;
    short* ctx = Vtb + (size_t)BB * HH * SS * EE;             // 8 MB

    int n4 = BB * SS * DD / 4;
    convert_x_kernel<<<n4 / 256, 256, 0, stream>>>(x, xb, n4);
    transpose_w_kernel<<<dim3(16, 16), 256, 0, stream>>>(Wq, wqt, DD);
    transpose_w_kernel<<<dim3(16, 16), 256, 0, stream>>>(Wk, wkt, DD);
    transpose_w_kernel<<<dim3(16, 16), 256, 0, stream>>>(Wv, wvt, DD);
    transpose_w_kernel<<<dim3(16, 1), 256, 0, stream>>>(W, wot, HH * EE);

    qkv_gemm<<<768, 256, 0, stream>>>(xb, wqt, Qb, Kb, Vtb);
    attn_kernel<<<1024, 256, 0, stream>>>(Qb, Kb, Vtb, ctx);
    outproj_kernel<<<64, 256, 0, stream>>>(ctx, wot, out);
}

// Round 6
// 115.721 us; speedup vs baseline: 2.1103x; 1.2438x over previous
//
#include <hip/hip_runtime.h>
#include <hip/hip_bf16.h>
#include <cstdint>
#include <cstddef>

#define BB 2
#define SS 2048
#define DD 1024
#define HH 16
#define EE 64

typedef short bf16x8 __attribute__((ext_vector_type(8)));
typedef short s4 __attribute__((ext_vector_type(4)));
typedef float f32x4 __attribute__((ext_vector_type(4)));
typedef float float4v __attribute__((ext_vector_type(4)));

#define GLDS(gp, lp) __builtin_amdgcn_global_load_lds( \
    (const __attribute__((address_space(1))) void*)(gp), \
    (__attribute__((address_space(3))) void*)(lp), 16, 0, 0)

static __device__ __forceinline__ short f2bf(float f) {
    union { float f; uint32_t u; } v; v.f = f;
    uint32_t r = (v.u + 0x7fffu + ((v.u >> 16) & 1u)) >> 16;
    return (short)r;
}

// ---------------- fp32 -> bf16 convert (vectorized) ----------------
__global__ void convert_x_kernel(const float* __restrict__ x, short* __restrict__ xb, int n4) {
    int i = blockIdx.x * blockDim.x + threadIdx.x;
    if (i >= n4) return;
    float4v v = ((const float4v*)x)[i];
    s4 o; o[0] = f2bf(v[0]); o[1] = f2bf(v[1]); o[2] = f2bf(v[2]); o[3] = f2bf(v[3]);
    ((s4*)xb)[i] = o;
}

// ------------- weight transpose+convert: 3x [16][1024 x 64] -> [16][64 x 1024] bf16 -------------
// grid (16, 48): blockIdx.y = which*16 + mtx
__global__ void transpose_w3_kernel(const float* __restrict__ Wq,
                                    const float* __restrict__ Wk,
                                    const float* __restrict__ Wv,
                                    short* __restrict__ dst) {
    __shared__ float tile[64][65];
    int which = blockIdx.y >> 4;
    int mtx = blockIdx.y & 15;
    const float* src = (which == 0) ? Wq : (which == 1) ? Wk : Wv;
    int r0 = blockIdx.x * 64;
    const float* s = src + (size_t)mtx * DD * 64;
    short* d = dst + (size_t)which * HH * EE * DD + (size_t)mtx * DD * 64;
    int t = threadIdx.x;
#pragma unroll
    for (int i = 0; i < 16; ++i) {
        int idx = t + i * 256;
        int r = idx >> 6, c = idx & 63;
        tile[r][c] = s[(size_t)(r0 + r) * 64 + c];
    }
    __syncthreads();
#pragma unroll
    for (int i = 0; i < 16; ++i) {
        int idx = t + i * 256;
        int e = idx >> 6, dd2 = idx & 63;
        d[(size_t)e * DD + r0 + dd2] = f2bf(tile[dd2][e]);
    }
}

// single-matrix transpose for the output weight W [1024,64] -> [64,1024]
__global__ void transpose_w_kernel(const float* __restrict__ src, short* __restrict__ dst, int R) {
    __shared__ float tile[64][65];
    int r0 = blockIdx.x * 64;
    int t = threadIdx.x;
#pragma unroll
    for (int i = 0; i < 16; ++i) {
        int idx = t + i * 256;
        int r = idx >> 6, c = idx & 63;
        tile[r][c] = src[(size_t)(r0 + r) * 64 + c];
    }
    __syncthreads();
#pragma unroll
    for (int i = 0; i < 16; ++i) {
        int idx = t + i * 256;
        int e = idx >> 6, dd2 = idx & 63;
        dst[(size_t)e * R + r0 + dd2] = f2bf(tile[dd2][e]);
    }
}

// ------------- QKV as one GEMM, 2-phase pipelined + XCD 2D chunking -------------
// C = X[4096,1024] @ Bt[3072,1024]^T. 128x128 tile, BK=32, double-buffered LDS,
// STAGE(next) issued before compute, one barrier/iter.
__global__ __launch_bounds__(256) void qkv_gemm(const short* __restrict__ A,
                                                const short* __restrict__ Bt,
                                                short* __restrict__ Qo,
                                                short* __restrict__ Ko,
                                                short* __restrict__ Vto) {
    __shared__ short As[2][128 * 32];
    __shared__ short Bs[2][128 * 32];
    int tid = threadIdx.x;
    int wv = tid >> 6, lane = tid & 63;
    int m = lane & 15, g = lane >> 4;
    int wr = wv >> 1, wc = wv & 1;

    // XCD 2D chunking: each XCD owns an 8mb x 12nb rectangle (A 2MB + B 3MB ~ L2).
    // nb-minor every 8 blocks for B-panel reuse. Bijective over 768 blocks.
    int xcd = blockIdx.x & 7, idx = blockIdx.x >> 3;       // idx in [0,96)
    int mb = (xcd & 3) * 8 + (idx & 7);
    int nb = (xcd >> 2) * 12 + (idx >> 3);
    int rowBase = mb * 128, colBase0 = nb * 128;

    int strow = wv * 16 + (lane >> 2);
    int stcol = (lane & 3) * 8;
    const short* a0 = A + (size_t)(rowBase + strow) * DD + stcol;
    const short* b0 = Bt + (size_t)(colBase0 + strow) * DD + stcol;

    auto STAGE = [&](int buf, int kt) {
        short* asd = &As[buf][0] + wv * 512;
        short* bsd = &Bs[buf][0] + wv * 512;
        GLDS(a0 + kt, asd);
        GLDS(a0 + kt + (size_t)64 * DD, asd + 2048);
        GLDS(b0 + kt, bsd);
        GLDS(b0 + kt + (size_t)64 * DD, bsd + 2048);
    };

    f32x4 acc[4][4];
#pragma unroll
    for (int i = 0; i < 4; ++i)
#pragma unroll
        for (int j = 0; j < 4; ++j) acc[i][j] = {0, 0, 0, 0};

    STAGE(0, 0);
    __syncthreads();                    // drains vmcnt: buf0 ready

    for (int it = 0; it < DD / 32; ++it) {
        int cur = it & 1;
        if (it + 1 < DD / 32) STAGE(cur ^ 1, (it + 1) * 32);

        bf16x8 af[4], bfr[4];
#pragma unroll
        for (int mi = 0; mi < 4; ++mi)
            af[mi] = *(const bf16x8*)&As[cur][(wr * 64 + mi * 16 + m) * 32 + g * 8];
#pragma unroll
        for (int ni = 0; ni < 4; ++ni)
            bfr[ni] = *(const bf16x8*)&Bs[cur][(wc * 64 + ni * 16 + m) * 32 + g * 8];
#pragma unroll
        for (int mi = 0; mi < 4; ++mi)
#pragma unroll
            for (int ni = 0; ni < 4; ++ni)
                acc[mi][ni] = __builtin_amdgcn_mfma_f32_16x16x32_bf16(af[mi], bfr[ni], acc[mi][ni], 0, 0, 0);

        __syncthreads();                // drains next-STAGE vmcnt + protects cur reuse
    }

    int colBase = colBase0 + wc * 64;
    int mtx = colBase >> 10;
    int h = (colBase >> 6) & 15;
    int rb = rowBase + wr * 64;

    if (mtx == 0) {
#pragma unroll
        for (int mi = 0; mi < 4; ++mi)
#pragma unroll
            for (int ni = 0; ni < 4; ++ni)
#pragma unroll
                for (int r = 0; r < 4; ++r) {
                    int row = rb + mi * 16 + g * 4 + r;
                    int b = row >> 11, s = row & 2047;
                    Qo[((size_t)(b * HH + h) * SS + s) * EE + ni * 16 + m] = f2bf(acc[mi][ni][r] * 0.125f);
                }
    } else if (mtx == 1) {
#pragma unroll
        for (int mi = 0; mi < 4; ++mi)
#pragma unroll
            for (int ni = 0; ni < 4; ++ni)
#pragma unroll
                for (int r = 0; r < 4; ++r) {
                    int row = rb + mi * 16 + g * 4 + r;
                    int b = row >> 11, s = row & 2047;
                    Ko[((size_t)(b * HH + h) * SS + s) * EE + ni * 16 + m] = f2bf(acc[mi][ni][r]);
                }
    } else {
#pragma unroll
        for (int mi = 0; mi < 4; ++mi)
#pragma unroll
            for (int ni = 0; ni < 4; ++ni) {
                int row0 = rb + mi * 16 + g * 4;
                int b = row0 >> 11, s = row0 & 2047;
                s4 o; o[0] = f2bf(acc[mi][ni][0]); o[1] = f2bf(acc[mi][ni][1]);
                o[2] = f2bf(acc[mi][ni][2]); o[3] = f2bf(acc[mi][ni][3]);
                *(s4*)&Vto[((size_t)(b * HH + h) * EE + ni * 16 + m) * SS + s] = o;
            }
    }
}

// ------------- flash attention (causal), block-cooperative staged K/V -------------
__global__ __launch_bounds__(256) void attn_kernel(const short* __restrict__ Q,
                                                   const short* __restrict__ K,
                                                   const short* __restrict__ Vt,
                                                   short* __restrict__ ctx) {
    __shared__ short Ks[2][64 * 64];
    __shared__ short Vs[2][64 * 64];
    __shared__ short pl[4][16][72];
    int tid = threadIdx.x;
    int wv = tid >> 6, lane = tid & 63;
    int m = lane & 15, g = lane >> 4;
    int bid = blockIdx.x;
    int qblk = 31 - (bid >> 5);
    int bh = bid & 31;
    int b = bh >> 4, h = bh & 15;
    const short* Qb = Q + (size_t)bh * SS * EE;
    const short* Kb = K + (size_t)bh * SS * EE;
    const short* Vb = Vt + (size_t)bh * EE * SS;
    int qrow = qblk * 64 + wv * 16 + m;

    int srow = wv * 8 + (lane >> 3);
    int scol_s = (((lane & 7) * 16) ^ ((srow & 7) << 4)) >> 1;

    bf16x8 qa0 = *(const bf16x8*)(Qb + (size_t)qrow * EE + g * 8);
    bf16x8 qa1 = *(const bf16x8*)(Qb + (size_t)qrow * EE + 32 + g * 8);

    int sw = (m & 7) << 4;
    int c0 = (g * 16) ^ sw;
    int c1 = (64 + g * 16) ^ sw;

    float mreg = -INFINITY, lsum = 0.f;
    f32x4 o[4];
#pragma unroll
    for (int n = 0; n < 4; ++n) { o[n][0] = 0.f; o[n][1] = 0.f; o[n][2] = 0.f; o[n][3] = 0.f; }

    auto STAGE = [&](int nb, int t0) {
        short* kd = &Ks[0][0] + nb * 4096 + wv * 512;
        short* vd = &Vs[0][0] + nb * 4096 + wv * 512;
        const short* ksrc = Kb + (size_t)(t0 + srow) * EE + scol_s;
        const short* vsrc = Vb + (size_t)srow * SS + t0 + scol_s;
        GLDS(ksrc, kd);
        GLDS(ksrc + 32 * EE, kd + 2048);
        GLDS(vsrc, vd);
        GLDS(vsrc + (size_t)32 * SS, vd + 2048);
    };

    int ntile = qblk + 1;
    STAGE(0, 0);
    __syncthreads();

    for (int tt = 0; tt < ntile; ++tt) {
        if (tt + 1 < ntile) STAGE((tt + 1) & 1, (tt + 1) * 64);
        int t0 = tt * 64;
        const short* Ksb = &Ks[0][0] + (tt & 1) * 4096;
        const short* Vsb = &Vs[0][0] + (tt & 1) * 4096;

        f32x4 s[4] = {{0,0,0,0},{0,0,0,0},{0,0,0,0},{0,0,0,0}};
#pragma unroll
        for (int n = 0; n < 4; ++n) {
            const char* krow = (const char*)(Ksb + (n * 16 + m) * 64);
            bf16x8 kb0 = *(const bf16x8*)(krow + c0);
            s[n] = __builtin_amdgcn_mfma_f32_16x16x32_bf16(kb0, qa0, s[n], 0, 0, 0);
            bf16x8 kb1 = *(const bf16x8*)(krow + c1);
            s[n] = __builtin_amdgcn_mfma_f32_16x16x32_bf16(kb1, qa1, s[n], 0, 0, 0);
        }

        if (tt == qblk) {
#pragma unroll
            for (int n = 0; n < 4; ++n)
#pragma unroll
                for (int r = 0; r < 4; ++r)
                    if (t0 + n * 16 + g * 4 + r > qrow) s[n][r] = -INFINITY;
        }

        float mx = s[0][0];
#pragma unroll
        for (int n = 0; n < 4; ++n)
#pragma unroll
            for (int r = 0; r < 4; ++r) mx = fmaxf(mx, s[n][r]);
        mx = fmaxf(mx, __shfl_xor(mx, 16, 64));
        mx = fmaxf(mx, __shfl_xor(mx, 32, 64));

        if (!__all(mx <= mreg + 8.0f)) {
            float mn = fmaxf(mreg, mx);
            float al = __expf(mreg - mn);
            lsum *= al;
#pragma unroll
            for (int n = 0; n < 4; ++n)
#pragma unroll
                for (int r = 0; r < 4; ++r) o[n][r] *= al;
            mreg = mn;
        }

#pragma unroll
        for (int n = 0; n < 4; ++n) {
            s4 pk;
#pragma unroll
            for (int r = 0; r < 4; ++r) {
                float p = __expf(s[n][r] - mreg);
                lsum += p;
                pk[r] = f2bf(p);
            }
            *(s4*)&pl[wv][m][n * 16 + g * 4] = pk;
        }

#pragma unroll
        for (int ks = 0; ks < 2; ++ks) {
            bf16x8 pa = *(const bf16x8*)&pl[wv][m][ks * 32 + g * 8];
            int cv = ks ? c1 : c0;
#pragma unroll
            for (int n = 0; n < 4; ++n) {
                const char* vrow = (const char*)(Vsb + (n * 16 + m) * 64);
                bf16x8 vb = *(const bf16x8*)(vrow + cv);
                o[n] = __builtin_amdgcn_mfma_f32_16x16x32_bf16(vb, pa, o[n], 0, 0, 0);
            }
        }

        __syncthreads();
    }

    lsum += __shfl_xor(lsum, 16, 64);
    lsum += __shfl_xor(lsum, 32, 64);
    float inv = 1.0f / lsum;
    short* cb = ctx + (size_t)(b * SS + qrow) * (HH * EE) + h * EE;
#pragma unroll
    for (int n = 0; n < 4; ++n) {
        s4 pk;
#pragma unroll
        for (int r = 0; r < 4; ++r) pk[r] = f2bf(o[n][r] * inv);
        *(s4*)&cb[n * 16 + g * 4] = pk;
    }
}

// ------------- output projection: ctx [4096,1024] @ W [1024,64] -> out fp32 -------------
// grid 256: block = 16 output rows; 4 waves split K into 256-chunks; LDS reduce.
__global__ __launch_bounds__(256) void outproj_kernel(const short* __restrict__ ctx,
                                                      const short* __restrict__ wot,
                                                      float* __restrict__ out) {
    __shared__ float red[4][1024];
    int wv = threadIdx.x >> 6, lane = threadIdx.x & 63;
    int m = lane & 15, g = lane >> 4;
    int r0 = blockIdx.x * 16;
    const short* arow = ctx + (size_t)(r0 + m) * (HH * EE) + g * 8;
    const short* wb = wot + g * 8;
    f32x4 acc[4] = {{0,0,0,0},{0,0,0,0},{0,0,0,0},{0,0,0,0}};
    int k0 = wv * 256;
    for (int d0 = k0; d0 < k0 + 256; d0 += 32) {
        bf16x8 a = *(const bf16x8*)(arow + d0);
#pragma unroll
        for (int n = 0; n < 4; ++n) {
            bf16x8 bbf = *(const bf16x8*)(wb + (size_t)(n * 16 + m) * (HH * EE) + d0);
            acc[n] = __builtin_amdgcn_mfma_f32_16x16x32_bf16(a, bbf, acc[n], 0, 0, 0);
        }
    }
#pragma unroll
    for (int n = 0; n < 4; ++n)
#pragma unroll
        for (int r = 0; r < 4; ++r)
            red[wv][(g * 4 + r) * 64 + n * 16 + m] = acc[n][r];
    __syncthreads();
    int t = threadIdx.x;
    float4v sum = ((const float4v*)red[0])[t];
    sum += ((const float4v*)red[1])[t];
    sum += ((const float4v*)red[2])[t];
    sum += ((const float4v*)red[3])[t];
    ((float4v*)(out + (size_t)blockIdx.x * 1024))[t] = sum;
}

extern "C" void kernel_launch(void* const* d_in, const int* in_sizes, int n_in,
                              void* d_out, int out_size, void* d_ws, size_t ws_size,
                              hipStream_t stream) {
    const float* x  = (const float*)d_in[0];
    const float* Wq = (const float*)d_in[1];
    const float* Wk = (const float*)d_in[2];
    const float* Wv = (const float*)d_in[3];
    const float* W  = (const float*)d_in[4];
    float* out = (float*)d_out;

    char* w = (char*)d_ws;
    short* xb  = (short*)w;                                   // 8 MB
    short* wqt = (short*)(w + ((size_t)8 << 20));             // 2 MB each, contiguous = Bt
    short* wkt = wqt + (size_t)HH * EE * DD;
    short* wvt = wkt + (size_t)HH * EE * DD;
    short* wot = wvt + (size_t)HH * EE * DD;                  // 128 KB
    short* Qb  = wot + (size_t)64 * 1024;                     // 8 MB each
    short* Kb  = Qb + (size_t)BB * HH * SS * EE;
    short* Vtb = Kb + (size_t)BB * HH * SS * EE;
    short* ctx = Vtb + (size_t)BB * HH * SS * EE;             // 8 MB

    int n4 = BB * SS * DD / 4;
    convert_x_kernel<<<n4 / 256, 256, 0, stream>>>(x, xb, n4);
    transpose_w3_kernel<<<dim3(16, 48), 256, 0, stream>>>(Wq, Wk, Wv, wqt);
    transpose_w_kernel<<<dim3(16, 1), 256, 0, stream>>>(W, wot, HH * EE);

    qkv_gemm<<<768, 256, 0, stream>>>(xb, wqt, Qb, Kb, Vtb);
    attn_kernel<<<1024, 256, 0, stream>>>(Qb, Kb, Vtb, ctx);
    outproj_kernel<<<256, 256, 0, stream>>>(ctx, wot, out);
}

// Round 7
// 108.705 us; speedup vs baseline: 2.2465x; 1.0645x over previous
//
#include <hip/hip_runtime.h>
#include <hip/hip_bf16.h>
#include <cstdint>
#include <cstddef>

#define BB 2
#define SS 2048
#define DD 1024
#define HH 16
#define EE 64

typedef short bf16x8 __attribute__((ext_vector_type(8)));
typedef short s4 __attribute__((ext_vector_type(4)));
typedef float f32x4 __attribute__((ext_vector_type(4)));
typedef float float4v __attribute__((ext_vector_type(4)));

#define GLDS(gp, lp) __builtin_amdgcn_global_load_lds( \
    (const __attribute__((address_space(1))) void*)(gp), \
    (__attribute__((address_space(3))) void*)(lp), 16, 0, 0)

static __device__ __forceinline__ short f2bf(float f) {
    union { float f; uint32_t u; } v; v.f = f;
    uint32_t r = (v.u + 0x7fffu + ((v.u >> 16) & 1u)) >> 16;
    return (short)r;
}

// ---------------- fp32 -> bf16 convert (vectorized) ----------------
__global__ void convert_x_kernel(const float* __restrict__ x, short* __restrict__ xb, int n4) {
    int i = blockIdx.x * blockDim.x + threadIdx.x;
    if (i >= n4) return;
    float4v v = ((const float4v*)x)[i];
    s4 o; o[0] = f2bf(v[0]); o[1] = f2bf(v[1]); o[2] = f2bf(v[2]); o[3] = f2bf(v[3]);
    ((s4*)xb)[i] = o;
}

// ------------- weight transpose+convert: 3x [16][1024 x 64] -> [16][64 x 1024] bf16 -------------
__global__ void transpose_w3_kernel(const float* __restrict__ Wq,
                                    const float* __restrict__ Wk,
                                    const float* __restrict__ Wv,
                                    short* __restrict__ dst) {
    __shared__ float tile[64][65];
    int which = blockIdx.y >> 4;
    int mtx = blockIdx.y & 15;
    const float* src = (which == 0) ? Wq : (which == 1) ? Wk : Wv;
    int r0 = blockIdx.x * 64;
    const float* s = src + (size_t)mtx * DD * 64;
    short* d = dst + (size_t)which * HH * EE * DD + (size_t)mtx * DD * 64;
    int t = threadIdx.x;
#pragma unroll
    for (int i = 0; i < 16; ++i) {
        int idx = t + i * 256;
        int r = idx >> 6, c = idx & 63;
        tile[r][c] = s[(size_t)(r0 + r) * 64 + c];
    }
    __syncthreads();
#pragma unroll
    for (int i = 0; i < 16; ++i) {
        int idx = t + i * 256;
        int e = idx >> 6, dd2 = idx & 63;
        d[(size_t)e * DD + r0 + dd2] = f2bf(tile[dd2][e]);
    }
}

__global__ void transpose_w_kernel(const float* __restrict__ src, short* __restrict__ dst, int R) {
    __shared__ float tile[64][65];
    int r0 = blockIdx.x * 64;
    int t = threadIdx.x;
#pragma unroll
    for (int i = 0; i < 16; ++i) {
        int idx = t + i * 256;
        int r = idx >> 6, c = idx & 63;
        tile[r][c] = src[(size_t)(r0 + r) * 64 + c];
    }
    __syncthreads();
#pragma unroll
    for (int i = 0; i < 16; ++i) {
        int idx = t + i * 256;
        int e = idx >> 6, dd2 = idx & 63;
        dst[(size_t)e * R + r0 + dd2] = f2bf(tile[dd2][e]);
    }
}

// ------------- QKV GEMM: 256x256 tile, BK=32, 8 waves, triple-buffer, counted vmcnt -------------
// LDS tile storage: [128 storage-rows][64 shorts] per matrix; storage row sr holds
// logical rows 2sr (shorts 0..31) and 2sr+1 (shorts 32..63); byte-in-row XOR ((sr&7)<<4)
// applied on BOTH staging source and read side (attn-validated swizzle family).
__global__ __launch_bounds__(512, 2) void qkv_gemm(const short* __restrict__ A,
                                                   const short* __restrict__ Bt,
                                                   short* __restrict__ Qo,
                                                   short* __restrict__ Ko,
                                                   short* __restrict__ Vto) {
    __shared__ __align__(16) short As3[3][128 * 64];
    __shared__ __align__(16) short Bs3[3][128 * 64];
    int tid = threadIdx.x;
    int wv = tid >> 6, lane = tid & 63;
    int m = lane & 15, g = lane >> 4;
    int wr = wv >> 2, wc = wv & 3;          // 2M x 4N wave grid; per-wave 128x64

    // XCD 2D chunking over 16mb x 12nb grid (192 blocks, bijective)
    int xcd = blockIdx.x & 7, idx = blockIdx.x >> 3;   // idx in [0,24)
    int mb = (xcd & 3) * 4 + (idx & 3);
    int nb = (xcd >> 2) * 6 + (idx >> 2);
    int rowBase = mb * 256, colBase0 = nb * 256;

    // staging geometry: load j covers 16B phys slot si = j*512 + tid
    int src_row[2], src_kcol[2];
#pragma unroll
    for (int j = 0; j < 2; ++j) {
        int si = j * 512 + tid;
        int sr = si >> 3, sp = si & 7;
        int sl = sp ^ (sr & 7);             // logical slot (involution within row)
        src_row[j] = 2 * sr + (sl >> 2);    // logical tile row 0..255
        src_kcol[j] = (sl & 3) * 8;         // shorts 0..24
    }
    const short* aP0 = A + (size_t)(rowBase + src_row[0]) * DD + src_kcol[0];
    const short* aP1 = A + (size_t)(rowBase + src_row[1]) * DD + src_kcol[1];
    const short* bP0 = Bt + (size_t)(colBase0 + src_row[0]) * DD + src_kcol[0];
    const short* bP1 = Bt + (size_t)(colBase0 + src_row[1]) * DD + src_kcol[1];
    int dst0 = (wv * 64) * 8;               // wave-uniform LDS short-offset, lane*16B auto
    int dst1 = (512 + wv * 64) * 8;

    f32x4 acc[8][4];
#pragma unroll
    for (int i = 0; i < 8; ++i)
#pragma unroll
        for (int j = 0; j < 4; ++j) acc[i][j] = {0, 0, 0, 0};

    // swizzled read byte-offset within 128B storage row
    int rdoff = ((m & 1) * 64 + g * 16) ^ (((m >> 1) & 7) << 4);
    int mh = m >> 1;

    auto STAGE = [&](int buf, int kt) {
        short* ab = &As3[buf][0];
        short* bb = &Bs3[buf][0];
        GLDS(aP0 + kt, ab + dst0);
        GLDS(aP1 + kt, ab + dst1);
        GLDS(bP0 + kt, bb + dst0);
        GLDS(bP1 + kt, bb + dst1);
    };

    auto COMPUTE = [&](int buf) {
        bf16x8 af[8], bfr[4];
#pragma unroll
        for (int mi = 0; mi < 8; ++mi)
            af[mi] = *(const bf16x8*)((const char*)&As3[buf][(wr * 64 + mi * 8 + mh) * 64] + rdoff);
#pragma unroll
        for (int ni = 0; ni < 4; ++ni)
            bfr[ni] = *(const bf16x8*)((const char*)&Bs3[buf][(wc * 32 + ni * 8 + mh) * 64] + rdoff);
        // reads complete, then release waves (next STAGE may overwrite this buffer)
        asm volatile("s_waitcnt lgkmcnt(0)\ns_barrier" ::: "memory");
        __builtin_amdgcn_s_setprio(1);
#pragma unroll
        for (int mi = 0; mi < 8; ++mi)
#pragma unroll
            for (int ni = 0; ni < 4; ++ni)
                acc[mi][ni] = __builtin_amdgcn_mfma_f32_16x16x32_bf16(af[mi], bfr[ni], acc[mi][ni], 0, 0, 0);
        __builtin_amdgcn_s_setprio(0);
    };

    STAGE(0, 0);
    STAGE(1, 32);
    for (int t = 0; t < 30; ++t) {
        STAGE((t + 2) % 3, (t + 2) * 32);
        // oldest 4 loads (tile t) complete in every wave -> tile t fully staged
        asm volatile("s_waitcnt vmcnt(8)\ns_barrier" ::: "memory");
        COMPUTE(t % 3);
    }
    asm volatile("s_waitcnt vmcnt(4)\ns_barrier" ::: "memory");
    COMPUTE(0);                              // t=30
    asm volatile("s_waitcnt vmcnt(0)\ns_barrier" ::: "memory");
    COMPUTE(1);                              // t=31

    // epilogue scatter
    int colw = colBase0 + wc * 64;
    int mtx = colw >> 10;                    // wave-uniform
    int h = (colw >> 6) & 15;
    int rb = rowBase + wr * 128;

    if (mtx == 0) {
#pragma unroll
        for (int mi = 0; mi < 8; ++mi)
#pragma unroll
            for (int ni = 0; ni < 4; ++ni)
#pragma unroll
                for (int r = 0; r < 4; ++r) {
                    int row = rb + mi * 16 + g * 4 + r;
                    int b = row >> 11, s = row & 2047;
                    Qo[((size_t)(b * HH + h) * SS + s) * EE + ni * 16 + m] = f2bf(acc[mi][ni][r] * 0.125f);
                }
    } else if (mtx == 1) {
#pragma unroll
        for (int mi = 0; mi < 8; ++mi)
#pragma unroll
            for (int ni = 0; ni < 4; ++ni)
#pragma unroll
                for (int r = 0; r < 4; ++r) {
                    int row = rb + mi * 16 + g * 4 + r;
                    int b = row >> 11, s = row & 2047;
                    Ko[((size_t)(b * HH + h) * SS + s) * EE + ni * 16 + m] = f2bf(acc[mi][ni][r]);
                }
    } else {
#pragma unroll
        for (int mi = 0; mi < 8; ++mi)
#pragma unroll
            for (int ni = 0; ni < 4; ++ni) {
                int row0 = rb + mi * 16 + g * 4;
                int b = row0 >> 11, s = row0 & 2047;
                s4 o; o[0] = f2bf(acc[mi][ni][0]); o[1] = f2bf(acc[mi][ni][1]);
                o[2] = f2bf(acc[mi][ni][2]); o[3] = f2bf(acc[mi][ni][3]);
                *(s4*)&Vto[((size_t)(b * HH + h) * EE + ni * 16 + m) * SS + s] = o;
            }
    }
}

// ------------- flash attention (causal), block-cooperative staged K/V -------------
__global__ __launch_bounds__(256) void attn_kernel(const short* __restrict__ Q,
                                                   const short* __restrict__ K,
                                                   const short* __restrict__ Vt,
                                                   short* __restrict__ ctx) {
    __shared__ __align__(16) short Ks[2][64 * 64];
    __shared__ __align__(16) short Vs[2][64 * 64];
    __shared__ __align__(16) short pl[4][16][72];
    int tid = threadIdx.x;
    int wv = tid >> 6, lane = tid & 63;
    int m = lane & 15, g = lane >> 4;
    int bid = blockIdx.x;
    int qblk = 31 - (bid >> 5);
    int bh = bid & 31;
    int b = bh >> 4, h = bh & 15;
    const short* Qb = Q + (size_t)bh * SS * EE;
    const short* Kb = K + (size_t)bh * SS * EE;
    const short* Vb = Vt + (size_t)bh * EE * SS;
    int qrow = qblk * 64 + wv * 16 + m;

    int srow = wv * 8 + (lane >> 3);
    int scol_s = (((lane & 7) * 16) ^ ((srow & 7) << 4)) >> 1;

    bf16x8 qa0 = *(const bf16x8*)(Qb + (size_t)qrow * EE + g * 8);
    bf16x8 qa1 = *(const bf16x8*)(Qb + (size_t)qrow * EE + 32 + g * 8);

    int sw = (m & 7) << 4;
    int c0 = (g * 16) ^ sw;
    int c1 = (64 + g * 16) ^ sw;

    float mreg = -INFINITY, lsum = 0.f;
    f32x4 o[4];
#pragma unroll
    for (int n = 0; n < 4; ++n) { o[n][0] = 0.f; o[n][1] = 0.f; o[n][2] = 0.f; o[n][3] = 0.f; }

    auto STAGE = [&](int nb, int t0) {
        short* kd = &Ks[0][0] + nb * 4096 + wv * 512;
        short* vd = &Vs[0][0] + nb * 4096 + wv * 512;
        const short* ksrc = Kb + (size_t)(t0 + srow) * EE + scol_s;
        const short* vsrc = Vb + (size_t)srow * SS + t0 + scol_s;
        GLDS(ksrc, kd);
        GLDS(ksrc + 32 * EE, kd + 2048);
        GLDS(vsrc, vd);
        GLDS(vsrc + (size_t)32 * SS, vd + 2048);
    };

    int ntile = qblk + 1;
    STAGE(0, 0);
    __syncthreads();

    for (int tt = 0; tt < ntile; ++tt) {
        if (tt + 1 < ntile) STAGE((tt + 1) & 1, (tt + 1) * 64);
        int t0 = tt * 64;
        const short* Ksb = &Ks[0][0] + (tt & 1) * 4096;
        const short* Vsb = &Vs[0][0] + (tt & 1) * 4096;

        f32x4 s[4] = {{0,0,0,0},{0,0,0,0},{0,0,0,0},{0,0,0,0}};
#pragma unroll
        for (int n = 0; n < 4; ++n) {
            const char* krow = (const char*)(Ksb + (n * 16 + m) * 64);
            bf16x8 kb0 = *(const bf16x8*)(krow + c0);
            s[n] = __builtin_amdgcn_mfma_f32_16x16x32_bf16(kb0, qa0, s[n], 0, 0, 0);
            bf16x8 kb1 = *(const bf16x8*)(krow + c1);
            s[n] = __builtin_amdgcn_mfma_f32_16x16x32_bf16(kb1, qa1, s[n], 0, 0, 0);
        }

        if (tt == qblk) {
#pragma unroll
            for (int n = 0; n < 4; ++n)
#pragma unroll
                for (int r = 0; r < 4; ++r)
                    if (t0 + n * 16 + g * 4 + r > qrow) s[n][r] = -INFINITY;
        }

        float mx = s[0][0];
#pragma unroll
        for (int n = 0; n < 4; ++n)
#pragma unroll
            for (int r = 0; r < 4; ++r) mx = fmaxf(mx, s[n][r]);
        mx = fmaxf(mx, __shfl_xor(mx, 16, 64));
        mx = fmaxf(mx, __shfl_xor(mx, 32, 64));

        if (!__all(mx <= mreg + 8.0f)) {
            float mn = fmaxf(mreg, mx);
            float al = __expf(mreg - mn);
            lsum *= al;
#pragma unroll
            for (int n = 0; n < 4; ++n)
#pragma unroll
                for (int r = 0; r < 4; ++r) o[n][r] *= al;
            mreg = mn;
        }

#pragma unroll
        for (int n = 0; n < 4; ++n) {
            s4 pk;
#pragma unroll
            for (int r = 0; r < 4; ++r) {
                float p = __expf(s[n][r] - mreg);
                lsum += p;
                pk[r] = f2bf(p);
            }
            *(s4*)&pl[wv][m][n * 16 + g * 4] = pk;
        }

#pragma unroll
        for (int ks = 0; ks < 2; ++ks) {
            bf16x8 pa = *(const bf16x8*)&pl[wv][m][ks * 32 + g * 8];
            int cv = ks ? c1 : c0;
#pragma unroll
            for (int n = 0; n < 4; ++n) {
                const char* vrow = (const char*)(Vsb + (n * 16 + m) * 64);
                bf16x8 vb = *(const bf16x8*)(vrow + cv);
                o[n] = __builtin_amdgcn_mfma_f32_16x16x32_bf16(vb, pa, o[n], 0, 0, 0);
            }
        }

        __syncthreads();
    }

    lsum += __shfl_xor(lsum, 16, 64);
    lsum += __shfl_xor(lsum, 32, 64);
    float inv = 1.0f / lsum;
    short* cb = ctx + (size_t)(b * SS + qrow) * (HH * EE) + h * EE;
#pragma unroll
    for (int n = 0; n < 4; ++n) {
        s4 pk;
#pragma unroll
        for (int r = 0; r < 4; ++r) pk[r] = f2bf(o[n][r] * inv);
        *(s4*)&cb[n * 16 + g * 4] = pk;
    }
}

// ------------- output projection: ctx [4096,1024] @ W [1024,64] -> out fp32 -------------
__global__ __launch_bounds__(256) void outproj_kernel(const short* __restrict__ ctx,
                                                      const short* __restrict__ wot,
                                                      float* __restrict__ out) {
    __shared__ float red[4][1024];
    int wv = threadIdx.x >> 6, lane = threadIdx.x & 63;
    int m = lane & 15, g = lane >> 4;
    int r0 = blockIdx.x * 16;
    const short* arow = ctx + (size_t)(r0 + m) * (HH * EE) + g * 8;
    const short* wb = wot + g * 8;
    f32x4 acc[4] = {{0,0,0,0},{0,0,0,0},{0,0,0,0},{0,0,0,0}};
    int k0 = wv * 256;
    for (int d0 = k0; d0 < k0 + 256; d0 += 32) {
        bf16x8 a = *(const bf16x8*)(arow + d0);
#pragma unroll
        for (int n = 0; n < 4; ++n) {
            bf16x8 bbf = *(const bf16x8*)(wb + (size_t)(n * 16 + m) * (HH * EE) + d0);
            acc[n] = __builtin_amdgcn_mfma_f32_16x16x32_bf16(a, bbf, acc[n], 0, 0, 0);
        }
    }
#pragma unroll
    for (int n = 0; n < 4; ++n)
#pragma unroll
        for (int r = 0; r < 4; ++r)
            red[wv][(g * 4 + r) * 64 + n * 16 + m] = acc[n][r];
    __syncthreads();
    int t = threadIdx.x;
    float4v sum = ((const float4v*)red[0])[t];
    sum += ((const float4v*)red[1])[t];
    sum += ((const float4v*)red[2])[t];
    sum += ((const float4v*)red[3])[t];
    ((float4v*)(out + (size_t)blockIdx.x * 1024))[t] = sum;
}

extern "C" void kernel_launch(void* const* d_in, const int* in_sizes, int n_in,
                              void* d_out, int out_size, void* d_ws, size_t ws_size,
                              hipStream_t stream) {
    const float* x  = (const float*)d_in[0];
    const float* Wq = (const float*)d_in[1];
    const float* Wk = (const float*)d_in[2];
    const float* Wv = (const float*)d_in[3];
    const float* W  = (const float*)d_in[4];
    float* out = (float*)d_out;

    char* w = (char*)d_ws;
    short* xb  = (short*)w;                                   // 8 MB
    short* wqt = (short*)(w + ((size_t)8 << 20));             // 2 MB each, contiguous = Bt
    short* wkt = wqt + (size_t)HH * EE * DD;
    short* wvt = wkt + (size_t)HH * EE * DD;
    short* wot = wvt + (size_t)HH * EE * DD;                  // 128 KB
    short* Qb  = wot + (size_t)64 * 1024;                     // 8 MB each
    short* Kb  = Qb + (size_t)BB * HH * SS * EE;
    short* Vtb = Kb + (size_t)BB * HH * SS * EE;
    short* ctx = Vtb + (size_t)BB * HH * SS * EE;             // 8 MB

    int n4 = BB * SS * DD / 4;
    convert_x_kernel<<<n4 / 256, 256, 0, stream>>>(x, xb, n4);
    transpose_w3_kernel<<<dim3(16, 48), 256, 0, stream>>>(Wq, Wk, Wv, wqt);
    transpose_w_kernel<<<dim3(16, 1), 256, 0, stream>>>(W, wot, HH * EE);

    qkv_gemm<<<192, 512, 0, stream>>>(xb, wqt, Qb, Kb, Vtb);
    attn_kernel<<<1024, 256, 0, stream>>>(Qb, Kb, Vtb, ctx);
    outproj_kernel<<<256, 256, 0, stream>>>(ctx, wot, out);
}